// Round 3
// baseline (29043.759 us; speedup 1.0000x reference)
//
#include <hip/hip_runtime.h>
#include <math.h>

// Problem sizes
#define T_N 900
#define H_N 400
#define C_N 73
#define F_N 240
#define B_N 32
#define G4H 1600          // 4*H
#define BT  (B_N * T_N)   // 28800

// ---- time chunking ----
#define TC    180                  // chunk length (900 = 5 * 180)
#define NCHUNK (T_N / TC)          // 5
#define MROWS (B_N * TC)           // 5760 rows per chunk (per lstm)

// ---- workspace layout (in floats), total ~23.14M floats = 92.6 MB ----
#define XZC_OFF 0ULL
#define XZC_SZ  ((size_t)MROWS * G4H)          // 9,216,000 per lstm
#define HSC_OFF (XZC_OFF + 2 * XZC_SZ)         // hs chunk: [2][B][TC][H]
#define HSC_SZ  ((size_t)MROWS * H_N)          // 2,304,000 per lstm
#define HB_OFF  (HSC_OFF + 2 * HSC_SZ)         // h broadcast buffers
#define HB_SZ   ((size_t)2 * 4 * 2 * 8 * H_N)  // [2][4 grp][2 parity][8][400]
#define CNT_OFF (HB_OFF + HB_SZ)               // barrier counters (ints)
#define CNT_SZ  1024
#define STH_OFF (CNT_OFF + CNT_SZ)             // h state [2][32][400]
#define STC_OFF (STH_OFF + 2 * B_N * H_N)      // c state [2][32][400]
#define WS_TOTAL (STC_OFF + 2 * B_N * H_N)

// ---- recurrence config ----
#define RG   8     // batch rows per row-group
#define NGRP 4     // row groups  (4*8 = 32 = B)
#define NBLK 25    // hidden-unit blocks per lstm (25*16 = 400 = H)
#define HSZ  16    // hidden units per block
#define KCH  100   // k-chunk per wave (4 waves * 100 = 400 = H)

__device__ __forceinline__ float sigf(float x) {
    return 1.0f / (1.0f + expf(-x));   // precise exp: 900-step drift safety
}

// ============================================================
// Kernel 1: xz[chunk] = x[:, t0:t0+TC, :] @ Wx + b   for both LSTMs.
// Chunk C = [2][5760][1600].  BM=128, BN=128, BK=16, 256 thr, 8x8/thread.
// ============================================================
#define GM_BM 128
#define GM_BN 128
#define GM_BK 16

__global__ __launch_bounds__(256)
void xz_gemm(const float* __restrict__ x,
             const float* __restrict__ Wx_c, const float* __restrict__ b_c,
             const float* __restrict__ Wx_l, const float* __restrict__ b_l,
             float* __restrict__ xzc, int t0)
{
    const int L = blockIdx.z;
    const float* W    = L ? Wx_l : Wx_c;
    const float* bias = L ? b_l  : b_c;
    float* out = xzc + (size_t)L * XZC_SZ;

    const int m0 = blockIdx.y * GM_BM;
    const int n0 = blockIdx.x * GM_BN;
    const int tid = threadIdx.x;

    __shared__ float As[GM_BK][GM_BM + 4];   // transposed A tile
    __shared__ float Bs[GM_BK][GM_BN + 4];

    const int ty = tid >> 4;       // 0..15
    const int tx = tid & 15;       // 0..15

    float acc[8][8];
#pragma unroll
    for (int i = 0; i < 8; ++i)
#pragma unroll
        for (int j = 0; j < 8; ++j) acc[i][j] = 0.0f;

    const int ar = tid & 127;             // A row in tile
    const int aq = (tid >> 7) * 8;        // A k offset 0/8
    const int kr = tid >> 5;              // B: k-row pair id 0..7
    const int bc = (tid & 31) * 4;        // B: col*4

    // chunk row -> global x row
    const int mrow = m0 + ar;             // 0..5759
    const int bb   = mrow / TC;
    const int ss   = mrow - bb * TC;
    const float* arow = x + ((size_t)bb * T_N + t0 + ss) * F_N;

    for (int k0 = 0; k0 < F_N; k0 += GM_BK) {
        // stage A (128 rows x 16 k), transposed into As[k][row]
        {
            const float* ap = arow + k0 + aq;
            float4 a0 = *(const float4*)ap;
            float4 a1 = *(const float4*)(ap + 4);
            As[aq + 0][ar] = a0.x; As[aq + 1][ar] = a0.y;
            As[aq + 2][ar] = a0.z; As[aq + 3][ar] = a0.w;
            As[aq + 4][ar] = a1.x; As[aq + 5][ar] = a1.y;
            As[aq + 6][ar] = a1.z; As[aq + 7][ar] = a1.w;
        }
        // stage B (16 k x 128 cols), guard cols >= 1600
#pragma unroll
        for (int kk = kr * 2; kk < kr * 2 + 2; ++kk) {
            const float* wp = W + (size_t)(k0 + kk) * G4H;
#pragma unroll
            for (int q = 0; q < 4; ++q) {
                int gc = n0 + bc + q;
                Bs[kk][bc + q] = (gc < G4H) ? wp[gc] : 0.0f;
            }
        }
        __syncthreads();

#pragma unroll
        for (int kk = 0; kk < GM_BK; ++kk) {
            float a[8], b[8];
            *(float4*)&a[0] = *(const float4*)&As[kk][ty * 8];
            *(float4*)&a[4] = *(const float4*)&As[kk][ty * 8 + 4];
            *(float4*)&b[0] = *(const float4*)&Bs[kk][tx * 8];
            *(float4*)&b[4] = *(const float4*)&Bs[kk][tx * 8 + 4];
#pragma unroll
            for (int i = 0; i < 8; ++i)
#pragma unroll
                for (int j = 0; j < 8; ++j)
                    acc[i][j] = fmaf(a[i], b[j], acc[i][j]);
        }
        __syncthreads();
    }

#pragma unroll
    for (int i = 0; i < 8; ++i) {
        const int m = m0 + ty * 8 + i;
#pragma unroll
        for (int j = 0; j < 8; ++j) {
            const int c = n0 + tx * 8 + j;
            if (c < G4H)
                out[(size_t)m * G4H + c] = acc[i][j] + bias[c];
        }
    }
}

// ============================================================
// Kernel 2: persistent masked-LSTM recurrence, one time-chunk,
// both LSTMs.  grid = 200 blocks: [2 lstm][4 grp][25 unit-blocks],
// 256 threads.  Wh slice in VGPRs (reloaded per chunk).
// Per-domain (25-block) spin barrier each step through global h buffer.
// Counter accumulates across chunks: after step t, count = 25*(t+1).
// ============================================================
__global__ __launch_bounds__(256)
void lstm_rec(const float* __restrict__ Wh_c, const float* __restrict__ Wh_l,
              const int* __restrict__ seq_len,
              const float* __restrict__ xzc,
              float* __restrict__ hsc,
              float* __restrict__ hbuf,
              int* __restrict__ cnt,
              float* __restrict__ st_h, float* __restrict__ st_c,
              int t0)
{
    __shared__ float hsm[RG][404];        // staged h(t), padded rows
    __shared__ float part[4][RG][64];     // per-wave partial sums

    const int bid = blockIdx.x;
    const int L   = bid / (NGRP * NBLK);
    const int rem = bid % (NGRP * NBLK);
    const int g   = rem / NBLK;
    const int nb  = rem % NBLK;
    const int tid  = threadIdx.x;
    const int wave = tid >> 6;
    const int lane = tid & 63;

    const float* Wh = L ? Wh_l : Wh_c;
    const float* xz = xzc + (size_t)L * XZC_SZ;
    float* hs = hsc + (size_t)L * HSC_SZ;
    float* hb = hbuf + (size_t)(L * NGRP + g) * (2 * RG * H_N);
    int* mycnt = cnt + (L * NGRP + g) * 64;   // own cacheline per domain

    // ---- load Wh slice into registers (per chunk) ----
    const int gate = lane >> 4;            // 0..3
    const int jj_l = lane & 15;
    const int gcol = gate * H_N + nb * HSZ + jj_l;   // column in [0,1600)
    float wreg[KCH];
    {
        const float* wp = Wh + (size_t)(wave * KCH) * G4H + gcol;
#pragma unroll
        for (int kk = 0; kk < KCH; ++kk) wreg[kk] = wp[(size_t)kk * G4H];
    }

    // ---- row-group max length (uniform across the 25-block domain) ----
    int maxlen = 0;
#pragma unroll
    for (int r = 0; r < RG; ++r) {
        int v = seq_len[g * RG + r];
        maxlen = v > maxlen ? v : maxlen;
    }

    const int t1 = t0 + TC;
    int tse = maxlen < t1 ? maxlen : t1;      // sync-loop end (global t)

    // ---- per-thread persistent state (tid < 128): (row rr, unit jjs) ----
    const int rr  = tid >> 4;
    const int jjs = tid & 15;
    const int bidx = g * RG + rr;                // batch index (tid<128)
    const int uu   = nb * HSZ + jjs;             // hidden unit
    const int mylen = (tid < 128) ? seq_len[bidx] : 0;
    const int stidx = (L * B_N + bidx) * H_N + uu;
    float cst = 0.0f, hst = 0.0f;
    if (tid < 128 && t0 > 0) {
        hst = st_h[stidx];
        cst = st_c[stidx];
    }

    // prefetch xz for first sync step
    float xzn[4] = {0.f, 0.f, 0.f, 0.f};
    if (tid < 128 && t0 < tse) {
#pragma unroll
        for (int q = 0; q < 4; ++q)
            xzn[q] = xz[(size_t)bidx * TC * G4H + q * H_N + uu];
    }

    for (int t = t0; t < tse; ++t) {
        const int s = t - t0;                 // chunk-local step
        if (t > 0) {
            if (tid == 0) {
                const int target = NBLK * t;
                while (__hip_atomic_load(mycnt, __ATOMIC_RELAXED,
                                         __HIP_MEMORY_SCOPE_AGENT) < target)
                    __builtin_amdgcn_s_sleep(1);
            }
            __syncthreads();
            __threadfence();   // acquire: see remote h writes
        }

        // ---- stage h(t) (parity t&1) into LDS ----
        {
            const float* hsrc = hb + (size_t)(t & 1) * (RG * H_N);
            for (int i = tid; i < (RG * H_N) / 4; i += 256) {
                float4 v = ((const float4*)hsrc)[i];
                int f = i * 4;
                int r = f / H_N;
                int k = f - r * H_N;
                *(float4*)&hsm[r][k] = v;
            }
        }
        __syncthreads();

        // ---- z partial: acc[r] = sum_k wreg[k] * h[r][k] (per-wave k-chunk) ----
        float acc[RG];
#pragma unroll
        for (int r = 0; r < RG; ++r) acc[r] = 0.0f;
#pragma unroll
        for (int k4 = 0; k4 < KCH / 4; ++k4) {
            float4 hv[RG];
#pragma unroll
            for (int r = 0; r < RG; ++r)
                hv[r] = *(const float4*)&hsm[r][wave * KCH + k4 * 4];
            float w0 = wreg[k4 * 4 + 0];
            float w1 = wreg[k4 * 4 + 1];
            float w2 = wreg[k4 * 4 + 2];
            float w3 = wreg[k4 * 4 + 3];
#pragma unroll
            for (int r = 0; r < RG; ++r) {
                acc[r] = fmaf(w0, hv[r].x, acc[r]);
                acc[r] = fmaf(w1, hv[r].y, acc[r]);
                acc[r] = fmaf(w2, hv[r].z, acc[r]);
                acc[r] = fmaf(w3, hv[r].w, acc[r]);
            }
        }
#pragma unroll
        for (int r = 0; r < RG; ++r) part[wave][r][lane] = acc[r];
        __syncthreads();

        // ---- gate math + state update (tid < 128) ----
        if (tid < 128) {
            float z[4];
#pragma unroll
            for (int q = 0; q < 4; ++q) {
                const int c = q * HSZ + jjs;
                z[q] = part[0][rr][c] + part[1][rr][c] +
                       part[2][rr][c] + part[3][rr][c] + xzn[q];
            }
            const float iv = sigf(z[0]);
            const float fv = sigf(z[1]);
            const float gv = tanhf(z[2]);
            const float ov = sigf(z[3]);
            if (t < mylen) {                  // Keras mask: carry state if masked
                cst = fv * cst + iv * gv;
                hst = ov * tanhf(cst);
            }
            hs[((size_t)bidx * TC + s) * H_N + uu] = hst;   // frozen h too
            hb[(size_t)((t + 1) & 1) * (RG * H_N) + rr * H_N + uu] = hst;
            // prefetch next xz (hidden behind next barrier+stage+compute)
            if (t + 1 < tse) {
#pragma unroll
                for (int q = 0; q < 4; ++q)
                    xzn[q] = xz[((size_t)bidx * TC + (s + 1)) * G4H + q * H_N + uu];
            }
        }

        __threadfence();   // release h writes
        __syncthreads();
        if (tid == 0)
            __hip_atomic_fetch_add(mycnt, 1, __ATOMIC_RELEASE,
                                   __HIP_MEMORY_SCOPE_AGENT);
    }

    // ---- tail: domain finished (h frozen) — just emit hs rows ----
    {
        int ts = tse > t0 ? tse : t0;
        if (tid < 128) {
            for (int t = ts; t < t1; ++t) {
                const int s = t - t0;
                hs[((size_t)bidx * TC + s) * H_N + uu] = hst;
            }
        }
    }

    // ---- store carry state for next chunk ----
    if (tid < 128) {
        st_h[stidx] = hst;
        st_c[stidx] = cst;
    }
}

// ============================================================
// Kernel 3: logits[chunk] = hs[chunk] @ Wd + bd.
// (frozen h already materialized, so no clamping needed)
// BM=128 over 5760 rows, N=73(->80), BK=16.
// ============================================================
__global__ __launch_bounds__(256)
void dense_proj(const float* __restrict__ hsc,
                const float* __restrict__ Wd_c, const float* __restrict__ bd_c,
                const float* __restrict__ Wd_l, const float* __restrict__ bd_l,
                float* __restrict__ out, int t0)
{
    const int L = blockIdx.y;
    const float* hs = hsc + (size_t)L * HSC_SZ;
    const float* Wd = L ? Wd_l : Wd_c;
    const float* bd = L ? bd_l : bd_c;
    float* o = out + (size_t)L * ((size_t)BT * C_N);

    const int m0 = blockIdx.x * 128;
    const int tid = threadIdx.x;

    __shared__ float As[16][132];
    __shared__ float Bs[16][80];

    const int r  = tid >> 1;          // 0..127
    const int kq = (tid & 1) * 8;     // 0/8
    const float* ap_base = hs + (size_t)(m0 + r) * H_N + kq;

    const int ty = tid >> 4, tx = tid & 15;
    float acc[8][5];
#pragma unroll
    for (int i = 0; i < 8; ++i)
#pragma unroll
        for (int j = 0; j < 5; ++j) acc[i][j] = 0.0f;

    for (int k0 = 0; k0 < H_N; k0 += 16) {
        float4 a0 = *(const float4*)(ap_base + k0);
        float4 a1 = *(const float4*)(ap_base + k0 + 4);
        As[kq + 0][r] = a0.x; As[kq + 1][r] = a0.y;
        As[kq + 2][r] = a0.z; As[kq + 3][r] = a0.w;
        As[kq + 4][r] = a1.x; As[kq + 5][r] = a1.y;
        As[kq + 6][r] = a1.z; As[kq + 7][r] = a1.w;
        for (int i = tid; i < 16 * 80; i += 256) {
            int kk = i / 80, c = i - kk * 80;
            Bs[kk][c] = (c < C_N) ? Wd[(size_t)(k0 + kk) * C_N + c] : 0.0f;
        }
        __syncthreads();
#pragma unroll
        for (int kk = 0; kk < 16; ++kk) {
            float a[8], bb[5];
            *(float4*)&a[0] = *(const float4*)&As[kk][ty * 8];
            *(float4*)&a[4] = *(const float4*)&As[kk][ty * 8 + 4];
#pragma unroll
            for (int j = 0; j < 5; ++j) bb[j] = Bs[kk][tx * 5 + j];
#pragma unroll
            for (int i = 0; i < 8; ++i)
#pragma unroll
                for (int j = 0; j < 5; ++j)
                    acc[i][j] = fmaf(a[i], bb[j], acc[i][j]);
        }
        __syncthreads();
    }

    // chunk row -> global output row
#pragma unroll
    for (int i = 0; i < 8; ++i) {
        const int m = m0 + ty * 8 + i;        // 0..5759
        const int bb = m / TC;
        const int ssg = m - bb * TC + t0;     // global t
        float* orow = o + ((size_t)bb * T_N + ssg) * C_N;
#pragma unroll
        for (int j = 0; j < 5; ++j) {
            const int c = tx * 5 + j;
            if (c < C_N)
                orow[c] = acc[i][j] + bd[c];
        }
    }
}

// ============================================================
// Kernel 4: max |a - b|  -> scalar (atomicMax on int bits, vals >= 0)
// ============================================================
__global__ void maxdiff_k(const float* __restrict__ a,
                          const float* __restrict__ b,
                          int* __restrict__ outbits, size_t n)
{
    size_t i0 = (size_t)blockIdx.x * blockDim.x + threadIdx.x;
    float m = 0.0f;
    for (size_t i = i0; i < n; i += (size_t)gridDim.x * blockDim.x) {
        float d = fabsf(a[i] - b[i]);
        m = d > m ? d : m;
    }
#pragma unroll
    for (int off = 32; off > 0; off >>= 1) {
        float o = __shfl_down(m, off, 64);
        m = o > m ? o : m;
    }
    __shared__ float sm[4];
    if ((threadIdx.x & 63) == 0) sm[threadIdx.x >> 6] = m;
    __syncthreads();
    if (threadIdx.x == 0) {
        float mm = sm[0];
#pragma unroll
        for (int w = 1; w < 4; ++w) mm = sm[w] > mm ? sm[w] : mm;
        atomicMax(outbits, __float_as_int(mm));
    }
}

// ============================================================
extern "C" void kernel_launch(void* const* d_in, const int* in_sizes, int n_in,
                              void* d_out, int out_size, void* d_ws, size_t ws_size,
                              hipStream_t stream)
{
    const float* x    = (const float*)d_in[0];
    const int*   slen = (const int*)  d_in[1];
    const float* Wx_c = (const float*)d_in[2];
    const float* Wh_c = (const float*)d_in[3];
    const float* b_c  = (const float*)d_in[4];
    const float* Wx_l = (const float*)d_in[5];
    const float* Wh_l = (const float*)d_in[6];
    const float* b_l  = (const float*)d_in[7];
    const float* Wd_c = (const float*)d_in[8];
    const float* bd_c = (const float*)d_in[9];
    const float* Wd_l = (const float*)d_in[10];
    const float* bd_l = (const float*)d_in[11];

    float* ws    = (float*)d_ws;
    float* xzbuf = ws + XZC_OFF;
    float* hsbuf = ws + HSC_OFF;
    float* hbuf  = ws + HB_OFF;
    int*   cnt   = (int*)(ws + CNT_OFF);
    float* st_h  = ws + STH_OFF;
    float* st_c  = ws + STC_OFF;
    float* out   = (float*)d_out;

    // zero h-broadcast buffers + barrier counters + output scalar slot
    hipMemsetAsync(hbuf, 0, (size_t)(HB_SZ + CNT_SZ) * sizeof(float), stream);
    hipMemsetAsync(out + 2 * (size_t)BT * C_N, 0, sizeof(float), stream);

    for (int chunk = 0; chunk < NCHUNK; ++chunk) {
        const int t0 = chunk * TC;

        // 1) xz chunk = x[:, t0:t0+TC, :] @ Wx + b   (both LSTMs)
        {
            dim3 grid((G4H + GM_BN - 1) / GM_BN, MROWS / GM_BM, 2); // (13,45,2)
            xz_gemm<<<grid, 256, 0, stream>>>(x, Wx_c, b_c, Wx_l, b_l,
                                              xzbuf, t0);
        }
        // 2) recurrence chunk (200 blocks, both LSTMs concurrently)
        {
            lstm_rec<<<dim3(2 * NGRP * NBLK), dim3(256), 0, stream>>>(
                Wh_c, Wh_l, slen, xzbuf, hsbuf, hbuf, cnt, st_h, st_c, t0);
        }
        // 3) dense heads for this chunk
        {
            dim3 grid(MROWS / 128, 2);   // (45, 2)
            dense_proj<<<grid, 256, 0, stream>>>(hsbuf, Wd_c, bd_c,
                                                 Wd_l, bd_l, out, t0);
        }
    }

    // 4) max |logits_c - logits_l|
    maxdiff_k<<<dim3(1024), 256, 0, stream>>>(
        out, out + (size_t)BT * C_N, (int*)(out + 2 * (size_t)BT * C_N),
        (size_t)BT * C_N);
}

// Round 5
// 7810.780 us; speedup vs baseline: 3.7184x; 3.7184x over previous
//
#include <hip/hip_runtime.h>
#include <math.h>

// Problem sizes
#define T_N 900
#define H_N 400
#define C_N 73
#define F_N 240
#define B_N 32
#define G4H 1600          // 4*H
#define BT  (B_N * T_N)   // 28800

// ---- time chunking ----
#define TC    180                  // chunk length (900 = 5 * 180)
#define NCHUNK (T_N / TC)          // 5
#define MROWS (B_N * TC)           // 5760 rows per chunk (per lstm)

// ---- recurrence config ----
#define RG   8     // batch rows per row-group
#define NGRP 4     // row groups  (4*8 = 32 = B)
#define NBLK 25    // hidden-unit blocks per lstm (25*16 = 400 = H)
#define HSZ  16    // hidden units per block
#define KCH  100   // k-chunk per wave (4 waves * 100 = 400 = H)
#define HELEM (RG * H_N)           // 3200 h elements per domain

// ---- workspace layout (in floats) ----
#define XZC_OFF 0ULL
#define XZC_SZ  ((size_t)MROWS * G4H)          // 9,216,000 per lstm
#define HSC_OFF (XZC_OFF + 2 * XZC_SZ)         // hs chunk: [2][B][TC][H]
#define HSC_SZ  ((size_t)MROWS * H_N)          // 2,304,000 per lstm
#define HB_OFF  (HSC_OFF + 2 * HSC_SZ)         // tagged h broadcast (u64!)
#define HB_U64  ((size_t)2 * NGRP * 2 * HELEM) // [2 lstm][4 grp][2 parity][3200]
#define STH_OFF (HB_OFF + 2 * HB_U64)          // h state [2][32][400] (floats)
#define STC_OFF (STH_OFF + 2 * B_N * H_N)      // c state [2][32][400]
#define WS_TOTAL (STC_OFF + 2 * B_N * H_N)

typedef unsigned long long u64;

__device__ __forceinline__ float sigf(float x) {
    return 1.0f / (1.0f + expf(-x));   // precise exp: 900-step drift safety
}

// ============================================================
// Kernel 1: xz[chunk] = x[:, t0:t0+TC, :] @ Wx + b   for both LSTMs.
// Chunk C = [2][5760][1600].  BM=128, BN=128, BK=16, 256 thr, 8x8/thread.
// ============================================================
#define GM_BM 128
#define GM_BN 128
#define GM_BK 16

__global__ __launch_bounds__(256)
void xz_gemm(const float* __restrict__ x,
             const float* __restrict__ Wx_c, const float* __restrict__ b_c,
             const float* __restrict__ Wx_l, const float* __restrict__ b_l,
             float* __restrict__ xzc, int t0)
{
    const int L = blockIdx.z;
    const float* W    = L ? Wx_l : Wx_c;
    const float* bias = L ? b_l  : b_c;
    float* out = xzc + (size_t)L * XZC_SZ;

    const int m0 = blockIdx.y * GM_BM;
    const int n0 = blockIdx.x * GM_BN;
    const int tid = threadIdx.x;

    __shared__ float As[GM_BK][GM_BM + 4];   // transposed A tile
    __shared__ float Bs[GM_BK][GM_BN + 4];

    const int ty = tid >> 4;       // 0..15
    const int tx = tid & 15;       // 0..15

    float acc[8][8];
#pragma unroll
    for (int i = 0; i < 8; ++i)
#pragma unroll
        for (int j = 0; j < 8; ++j) acc[i][j] = 0.0f;

    const int ar = tid & 127;             // A row in tile
    const int aq = (tid >> 7) * 8;        // A k offset 0/8
    const int kr = tid >> 5;              // B: k-row pair id 0..7
    const int bc = (tid & 31) * 4;        // B: col*4

    // chunk row -> global x row
    const int mrow = m0 + ar;             // 0..5759
    const int bb   = mrow / TC;
    const int ss   = mrow - bb * TC;
    const float* arow = x + ((size_t)bb * T_N + t0 + ss) * F_N;

    for (int k0 = 0; k0 < F_N; k0 += GM_BK) {
        // stage A (128 rows x 16 k), transposed into As[k][row]
        {
            const float* ap = arow + k0 + aq;
            float4 a0 = *(const float4*)ap;
            float4 a1 = *(const float4*)(ap + 4);
            As[aq + 0][ar] = a0.x; As[aq + 1][ar] = a0.y;
            As[aq + 2][ar] = a0.z; As[aq + 3][ar] = a0.w;
            As[aq + 4][ar] = a1.x; As[aq + 5][ar] = a1.y;
            As[aq + 6][ar] = a1.z; As[aq + 7][ar] = a1.w;
        }
        // stage B (16 k x 128 cols), guard cols >= 1600
#pragma unroll
        for (int kk = kr * 2; kk < kr * 2 + 2; ++kk) {
            const float* wp = W + (size_t)(k0 + kk) * G4H;
#pragma unroll
            for (int q = 0; q < 4; ++q) {
                int gc = n0 + bc + q;
                Bs[kk][bc + q] = (gc < G4H) ? wp[gc] : 0.0f;
            }
        }
        __syncthreads();

#pragma unroll
        for (int kk = 0; kk < GM_BK; ++kk) {
            float a[8], b[8];
            *(float4*)&a[0] = *(const float4*)&As[kk][ty * 8];
            *(float4*)&a[4] = *(const float4*)&As[kk][ty * 8 + 4];
            *(float4*)&b[0] = *(const float4*)&Bs[kk][tx * 8];
            *(float4*)&b[4] = *(const float4*)&Bs[kk][tx * 8 + 4];
#pragma unroll
            for (int i = 0; i < 8; ++i)
#pragma unroll
                for (int j = 0; j < 8; ++j)
                    acc[i][j] = fmaf(a[i], b[j], acc[i][j]);
        }
        __syncthreads();
    }

#pragma unroll
    for (int i = 0; i < 8; ++i) {
        const int m = m0 + ty * 8 + i;
#pragma unroll
        for (int j = 0; j < 8; ++j) {
            const int c = n0 + tx * 8 + j;
            if (c < G4H)
                out[(size_t)m * G4H + c] = acc[i][j] + bias[c];
        }
    }
}

// ============================================================
// Kernel 2: persistent masked-LSTM recurrence, one time-chunk,
// both LSTMs.  grid = 200 blocks: [2 lstm][4 grp][25 unit-blocks].
// NO fences, NO barrier counter: h is exchanged via 8-byte tagged
// relaxed device-scope atomics {tag=t+1, h} in a parity (t&1) buffer.
// Readers poll for exact tag match; zero-init encodes {tag=0, h=0}.
// Deadlock-free with 2 parity buffers: a writer reaches tag t+2 for a
// buffer only after its own step-t+1 poll saw ALL tag-(t+1) stores,
// each of which happens after that block fully staged buffer t
// (ordered by the vmcnt(0) drain at __syncthreads).
// ============================================================
__global__ __launch_bounds__(256)
void lstm_rec(const float* __restrict__ Wh_c, const float* __restrict__ Wh_l,
              const int* __restrict__ seq_len,
              const float* __restrict__ xzc,
              float* __restrict__ hsc,
              u64* __restrict__ hb64,
              float* __restrict__ st_h, float* __restrict__ st_c,
              int t0)
{
    __shared__ float hsm[RG][404];        // staged h(t), padded rows
    __shared__ float part[4][RG][64];     // per-wave partial sums

    const int bid = blockIdx.x;
    const int L   = bid / (NGRP * NBLK);
    const int rem = bid % (NGRP * NBLK);
    const int g   = rem / NBLK;
    const int nb  = rem % NBLK;
    const int tid  = threadIdx.x;
    const int wave = tid >> 6;
    const int lane = tid & 63;

    const float* Wh = L ? Wh_l : Wh_c;
    const float* xz = xzc + (size_t)L * XZC_SZ;
    float* hs = hsc + (size_t)L * HSC_SZ;
    u64* hb = hb64 + (size_t)(L * NGRP + g) * (2 * HELEM);

    // ---- load Wh slice into registers (per chunk) ----
    const int gate = lane >> 4;            // 0..3
    const int jj_l = lane & 15;
    const int gcol = gate * H_N + nb * HSZ + jj_l;   // column in [0,1600)
    float wreg[KCH];
    {
        const float* wp = Wh + (size_t)(wave * KCH) * G4H + gcol;
#pragma unroll
        for (int kk = 0; kk < KCH; ++kk) wreg[kk] = wp[(size_t)kk * G4H];
    }

    // ---- row-group max length (uniform across the 25-block domain) ----
    int maxlen = 0;
#pragma unroll
    for (int r = 0; r < RG; ++r) {
        int v = seq_len[g * RG + r];
        maxlen = v > maxlen ? v : maxlen;
    }

    const int t1 = t0 + TC;
    const int tse = maxlen < t1 ? maxlen : t1;    // sync-loop end (global t)

    // ---- per-thread persistent state (tid < 128): (row rr, unit jjs) ----
    const int rr  = tid >> 4;
    const int jjs = tid & 15;
    const int bidx = g * RG + rr;                // batch index (tid<128)
    const int uu   = nb * HSZ + jjs;             // hidden unit
    const int mylen = (tid < 128) ? seq_len[bidx] : 0;
    const int stidx = (L * B_N + bidx) * H_N + uu;
    float cst = 0.0f, hst = 0.0f;
    if (tid < 128 && t0 > 0) {
        hst = st_h[stidx];
        cst = st_c[stidx];
    }

    // prefetch xz for first sync step
    float xzn[4] = {0.f, 0.f, 0.f, 0.f};
    if (tid < 128 && t0 < tse) {
#pragma unroll
        for (int q = 0; q < 4; ++q)
            xzn[q] = xz[(size_t)bidx * TC * G4H + q * H_N + uu];
    }

    for (int t = t0; t < tse; ++t) {
        const int s = t - t0;                 // chunk-local step

        // ---- poll + stage h(t): parity t&1, exact tag t ----
        {
            const u64* src = hb + (size_t)(t & 1) * HELEM;
            u64 vv[13];
#pragma unroll
            for (int i = 0; i < 13; ++i) {
                const int e = tid + (i << 8);
                if (e < HELEM)
                    vv[i] = __hip_atomic_load(src + e, __ATOMIC_RELAXED,
                                              __HIP_MEMORY_SCOPE_AGENT);
            }
#pragma unroll
            for (int i = 0; i < 13; ++i) {
                const int e = tid + (i << 8);
                if (e < HELEM) {
                    u64 xv = vv[i];
                    while ((unsigned)(xv >> 32) != (unsigned)t)
                        xv = __hip_atomic_load(src + e, __ATOMIC_RELAXED,
                                               __HIP_MEMORY_SCOPE_AGENT);
                    const int r = (int)((unsigned)e / 400u);
                    const int k = e - r * 400;
                    hsm[r][k] = __uint_as_float((unsigned)xv);
                }
            }
        }
        __syncthreads();

        // ---- z partial: acc[r] = sum_k wreg[k] * h[r][k] (per-wave k-chunk) ----
        float acc[RG];
#pragma unroll
        for (int r = 0; r < RG; ++r) acc[r] = 0.0f;
#pragma unroll
        for (int k4 = 0; k4 < KCH / 4; ++k4) {
            float4 hv[RG];
#pragma unroll
            for (int r = 0; r < RG; ++r)
                hv[r] = *(const float4*)&hsm[r][wave * KCH + k4 * 4];
            float w0 = wreg[k4 * 4 + 0];
            float w1 = wreg[k4 * 4 + 1];
            float w2 = wreg[k4 * 4 + 2];
            float w3 = wreg[k4 * 4 + 3];
#pragma unroll
            for (int r = 0; r < RG; ++r) {
                acc[r] = fmaf(w0, hv[r].x, acc[r]);
                acc[r] = fmaf(w1, hv[r].y, acc[r]);
                acc[r] = fmaf(w2, hv[r].z, acc[r]);
                acc[r] = fmaf(w3, hv[r].w, acc[r]);
            }
        }
#pragma unroll
        for (int r = 0; r < RG; ++r) part[wave][r][lane] = acc[r];
        __syncthreads();

        // ---- gate math + state update + publish (tid < 128) ----
        if (tid < 128) {
            float z[4];
#pragma unroll
            for (int q = 0; q < 4; ++q) {
                const int c = q * HSZ + jjs;
                z[q] = part[0][rr][c] + part[1][rr][c] +
                       part[2][rr][c] + part[3][rr][c] + xzn[q];
            }
            const float iv = sigf(z[0]);
            const float fv = sigf(z[1]);
            const float gv = tanhf(z[2]);
            const float ov = sigf(z[3]);
            if (t < mylen) {                  // Keras mask: carry state if masked
                cst = fv * cst + iv * gv;
                hst = ov * tanhf(cst);
            }
            hs[((size_t)bidx * TC + s) * H_N + uu] = hst;   // frozen h too

            // publish h(t+1) as {tag=t+1, value} into parity (t+1)&1
            const u64 pack = ((u64)(unsigned)(t + 1) << 32) |
                             (u64)__float_as_uint(hst);
            __hip_atomic_store(hb + (size_t)((t + 1) & 1) * HELEM +
                               (rr * H_N + uu),
                               pack, __ATOMIC_RELAXED,
                               __HIP_MEMORY_SCOPE_AGENT);

            // prefetch next xz (hidden behind next poll+stage+compute)
            if (t + 1 < tse) {
#pragma unroll
                for (int q = 0; q < 4; ++q)
                    xzn[q] = xz[((size_t)bidx * TC + (s + 1)) * G4H + q * H_N + uu];
            }
        }
    }

    // ---- tail: domain finished (h frozen) — just emit hs rows ----
    if (tid < 128) {
        const int ts = tse > t0 ? tse : t0;
        for (int t = ts; t < t1; ++t) {
            const int s = t - t0;
            hs[((size_t)bidx * TC + s) * H_N + uu] = hst;
        }
        // ---- store carry state for next chunk ----
        st_h[stidx] = hst;
        st_c[stidx] = cst;
    }
}

// ============================================================
// Kernel 3: logits[chunk] = hs[chunk] @ Wd + bd.
// (frozen h already materialized, so no clamping needed)
// BM=128 over 5760 rows, N=73(->80), BK=16.
// ============================================================
__global__ __launch_bounds__(256)
void dense_proj(const float* __restrict__ hsc,
                const float* __restrict__ Wd_c, const float* __restrict__ bd_c,
                const float* __restrict__ Wd_l, const float* __restrict__ bd_l,
                float* __restrict__ out, int t0)
{
    const int L = blockIdx.y;
    const float* hs = hsc + (size_t)L * HSC_SZ;
    const float* Wd = L ? Wd_l : Wd_c;
    const float* bd = L ? bd_l : bd_c;
    float* o = out + (size_t)L * ((size_t)BT * C_N);

    const int m0 = blockIdx.x * 128;
    const int tid = threadIdx.x;

    __shared__ float As[16][132];
    __shared__ float Bs[16][80];

    const int r  = tid >> 1;          // 0..127
    const int kq = (tid & 1) * 8;     // 0/8
    const float* ap_base = hs + (size_t)(m0 + r) * H_N + kq;

    const int ty = tid >> 4, tx = tid & 15;
    float acc[8][5];
#pragma unroll
    for (int i = 0; i < 8; ++i)
#pragma unroll
        for (int j = 0; j < 5; ++j) acc[i][j] = 0.0f;

    for (int k0 = 0; k0 < H_N; k0 += 16) {
        float4 a0 = *(const float4*)(ap_base + k0);
        float4 a1 = *(const float4*)(ap_base + k0 + 4);
        As[kq + 0][r] = a0.x; As[kq + 1][r] = a0.y;
        As[kq + 2][r] = a0.z; As[kq + 3][r] = a0.w;
        As[kq + 4][r] = a1.x; As[kq + 5][r] = a1.y;
        As[kq + 6][r] = a1.z; As[kq + 7][r] = a1.w;
        for (int i = tid; i < 16 * 80; i += 256) {
            int kk = i / 80, c = i - kk * 80;
            Bs[kk][c] = (c < C_N) ? Wd[(size_t)(k0 + kk) * C_N + c] : 0.0f;
        }
        __syncthreads();
#pragma unroll
        for (int kk = 0; kk < 16; ++kk) {
            float a[8], bb[5];
            *(float4*)&a[0] = *(const float4*)&As[kk][ty * 8];
            *(float4*)&a[4] = *(const float4*)&As[kk][ty * 8 + 4];
#pragma unroll
            for (int j = 0; j < 5; ++j) bb[j] = Bs[kk][tx * 5 + j];
#pragma unroll
            for (int i = 0; i < 8; ++i)
#pragma unroll
                for (int j = 0; j < 5; ++j)
                    acc[i][j] = fmaf(a[i], bb[j], acc[i][j]);
        }
        __syncthreads();
    }

    // chunk row -> global output row
#pragma unroll
    for (int i = 0; i < 8; ++i) {
        const int m = m0 + ty * 8 + i;        // 0..5759
        const int bb = m / TC;
        const int ssg = m - bb * TC + t0;     // global t
        float* orow = o + ((size_t)bb * T_N + ssg) * C_N;
#pragma unroll
        for (int j = 0; j < 5; ++j) {
            const int c = tx * 5 + j;
            if (c < C_N)
                orow[c] = acc[i][j] + bd[c];
        }
    }
}

// ============================================================
// Kernel 4: max |a - b|  -> scalar (atomicMax on int bits, vals >= 0)
// ============================================================
__global__ void maxdiff_k(const float* __restrict__ a,
                          const float* __restrict__ b,
                          int* __restrict__ outbits, size_t n)
{
    size_t i0 = (size_t)blockIdx.x * blockDim.x + threadIdx.x;
    float m = 0.0f;
    for (size_t i = i0; i < n; i += (size_t)gridDim.x * blockDim.x) {
        float d = fabsf(a[i] - b[i]);
        m = d > m ? d : m;
    }
#pragma unroll
    for (int off = 32; off > 0; off >>= 1) {
        float o = __shfl_down(m, off, 64);
        m = o > m ? o : m;
    }
    __shared__ float sm[4];
    if ((threadIdx.x & 63) == 0) sm[threadIdx.x >> 6] = m;
    __syncthreads();
    if (threadIdx.x == 0) {
        float mm = sm[0];
#pragma unroll
        for (int w = 1; w < 4; ++w) mm = sm[w] > mm ? sm[w] : mm;
        atomicMax(outbits, __float_as_int(mm));
    }
}

// ============================================================
extern "C" void kernel_launch(void* const* d_in, const int* in_sizes, int n_in,
                              void* d_out, int out_size, void* d_ws, size_t ws_size,
                              hipStream_t stream)
{
    const float* x    = (const float*)d_in[0];
    const int*   slen = (const int*)  d_in[1];
    const float* Wx_c = (const float*)d_in[2];
    const float* Wh_c = (const float*)d_in[3];
    const float* b_c  = (const float*)d_in[4];
    const float* Wx_l = (const float*)d_in[5];
    const float* Wh_l = (const float*)d_in[6];
    const float* b_l  = (const float*)d_in[7];
    const float* Wd_c = (const float*)d_in[8];
    const float* bd_c = (const float*)d_in[9];
    const float* Wd_l = (const float*)d_in[10];
    const float* bd_l = (const float*)d_in[11];

    float* ws    = (float*)d_ws;
    float* xzbuf = ws + XZC_OFF;
    float* hsbuf = ws + HSC_OFF;
    u64*   hb64  = (u64*)(ws + HB_OFF);
    float* st_h  = ws + STH_OFF;
    float* st_c  = ws + STC_OFF;
    float* out   = (float*)d_out;

    // zero tagged h-broadcast buffers ({tag=0, h=0} == all-zero bytes)
    // + output scalar slot
    hipMemsetAsync(hb64, 0, HB_U64 * sizeof(u64), stream);
    hipMemsetAsync(out + 2 * (size_t)BT * C_N, 0, sizeof(float), stream);

    for (int chunk = 0; chunk < NCHUNK; ++chunk) {
        const int t0 = chunk * TC;

        // 1) xz chunk = x[:, t0:t0+TC, :] @ Wx + b   (both LSTMs)
        {
            dim3 grid((G4H + GM_BN - 1) / GM_BN, MROWS / GM_BM, 2); // (13,45,2)
            xz_gemm<<<grid, 256, 0, stream>>>(x, Wx_c, b_c, Wx_l, b_l,
                                              xzbuf, t0);
        }
        // 2) recurrence chunk (200 blocks, both LSTMs concurrently)
        {
            lstm_rec<<<dim3(2 * NGRP * NBLK), dim3(256), 0, stream>>>(
                Wh_c, Wh_l, slen, xzbuf, hsbuf, hb64, st_h, st_c, t0);
        }
        // 3) dense heads for this chunk
        {
            dim3 grid(MROWS / 128, 2);   // (45, 2)
            dense_proj<<<grid, 256, 0, stream>>>(hsbuf, Wd_c, bd_c,
                                                 Wd_l, bd_l, out, t0);
        }
    }

    // 4) max |logits_c - logits_l|
    maxdiff_k<<<dim3(1024), 256, 0, stream>>>(
        out, out + (size_t)BT * C_N, (int*)(out + 2 * (size_t)BT * C_N),
        (size_t)BT * C_N);
}